// Round 6
// baseline (764.400 us; speedup 1.0000x reference)
//
#include <hip/hip_runtime.h>
#include <hip/hip_bf16.h>

typedef unsigned long long u64;
typedef unsigned int uint;
typedef __attribute__((ext_vector_type(8))) short short8;
typedef __attribute__((ext_vector_type(4))) float f32x4;

#define S_STEPS 101
#define BATCH   2048
#define DIN     120
#define HID     200
#define DOUT    12

// round-to-nearest-even f32 -> bf16 (as ushort)
__device__ __forceinline__ ushort f2bf(float f) {
  union { float f; unsigned u; } c; c.f = f;
  unsigned r = (c.u + 0x7FFFu + ((c.u >> 16) & 1u)) >> 16;
  return (ushort)r;
}
__device__ __forceinline__ float bf2f(ushort s) {
  union { unsigned u; float f; } c; c.u = ((unsigned)s) << 16;
  return c.f;
}
// packed f32x2 -> bf16x2 in one uint (v_cvt_pk_bf16_f32)
__device__ __forceinline__ uint pkbf(float a, float b) {
  __hip_bfloat162 h = __float22bfloat162_rn(make_float2(a, b));
  uint u; __builtin_memcpy(&u, &h, 4);
  return u;
}

// ---------------------------------------------------------------------------
// k_l1: fused layer-1. grid 128 x 512 (8 waves). Block = 16 batches, all t.
// Wave w owns h = 32w..32w+31 (2 n-tiles). W1 bf16 B-frags in regs.
// x staged per-t: [16][128] bf16 XOR-swizzled LDS, double-buffered,
// ONE barrier per t, depth-3 global register prefetch (load t+3 during t).
// Masks: u32 m1[t][8 words][2048 batches]; word w = h-bits 32w..32w+31.
// ---------------------------------------------------------------------------
__global__ __launch_bounds__(512) void k_l1(
    const float* __restrict__ x, const float* __restrict__ W1,
    const float* __restrict__ b1, uint* __restrict__ m1)
{
  __shared__ ushort A_sh[2][16 * 128];     // 8 KB double buffer
  const int tid  = threadIdx.x;
  const int lane = tid & 63;
  const int w    = tid >> 6;               // wave id 0..7 = mask word id
  const int b0   = blockIdx.x * 16;
  const int rr   = lane & 15;              // A-row(batch) & B/C-col(h) idx
  const int hi   = lane >> 4;

  // ---- B fragments (W1 bf16) + bias: 2 n-tiles per wave ----
  short8 bfrag[2][4];
  float  bv[2];
#pragma unroll
  for (int p = 0; p < 2; ++p) {
    const int n0 = w * 32 + p * 16 + rr;
    bv[p] = (n0 < HID) ? b1[n0] : 0.0f;
#pragma unroll
    for (int ks = 0; ks < 4; ++ks) {
      short8 bf = 0;
#pragma unroll
      for (int j = 0; j < 8; ++j) {
        const int k = ks * 32 + hi * 8 + j;
        float wv = (k < DIN && n0 < HID) ? W1[k * HID + n0] : 0.0f;
        bf[j] = (short)f2bf(wv);
      }
      bfrag[p][ks] = bf;
    }
  }

  // ---- zero the k=120..127 pad of both buffers (never rewritten) ----
  if (tid < 32) {
    const int bu = tid >> 4, r = tid & 15;
    *(short8*)((char*)&A_sh[bu][0] + r * 256 + (240 ^ ((r & 7) << 4))) = (short8)0;
  }

  // ---- x loaders: 480 threads, one float4 (4 floats of one (b,c) row) ----
  const bool ldr = tid < 480;
  int lb = 0, lc = 0, lg = 0;
  if (ldr) { lb = tid / 30; int rem = tid % 30; lc = rem / 10; lg = rem % 10; }
  const float* src = x + ((size_t)(b0 + lb) * 3 + lc) * (S_STEPS * 40) + lg * 4;
  const int wbyte = lb * 256 + (((lc * 40 + lg * 4) * 2) ^ ((lb & 7) << 4));

  float4 f1 = {0, 0, 0, 0}, f2 = {0, 0, 0, 0};
  if (ldr) {
    float4 f0 = *(const float4*)src;            // t=0
    uint2 u; u.x = pkbf(f0.x, f0.y); u.y = pkbf(f0.z, f0.w);
    *(uint2*)((char*)&A_sh[0][0] + wbyte) = u;
    f1 = *(const float4*)(src + 40);            // t=1
    f2 = *(const float4*)(src + 80);            // t=2
  }

  float vst[2][4] = {{0, 0, 0, 0}, {0, 0, 0, 0}};
  const int pg = lane >> 2, pr = lane & 3;
  __syncthreads();

#pragma unroll 1
  for (int t = 0; t < S_STEPS; ++t) {
    const int cur = t & 1;
    // A fragments from LDS
    short8 af[4];
#pragma unroll
    for (int ks = 0; ks < 4; ++ks)
      af[ks] = *(const short8*)((const char*)&A_sh[cur][0] +
                                rr * 256 + ((ks * 64 + hi * 16) ^ ((rr & 7) << 4)));
    // MFMA + LIF + ballot-pack (u32 word for this wave's 32 h)
    uint word = 0;
#pragma unroll
    for (int p = 0; p < 2; ++p) {
      f32x4 acc = {bv[p], bv[p], bv[p], bv[p]};
#pragma unroll
      for (int ks = 0; ks < 4; ++ks)
        acc = __builtin_amdgcn_mfma_f32_16x16x32_bf16(af[ks], bfrag[p][ks], acc, 0, 0, 0);
      u64 q0, q1, q2, q3;
      { float v = vst[p][0]; v = fmaf(0.5f, acc[0] - v, v); bool sp = v >= 1.0f; vst[p][0] = sp ? 0.f : v; q0 = __ballot(sp); }
      { float v = vst[p][1]; v = fmaf(0.5f, acc[1] - v, v); bool sp = v >= 1.0f; vst[p][1] = sp ? 0.f : v; q1 = __ballot(sp); }
      { float v = vst[p][2]; v = fmaf(0.5f, acc[2] - v, v); bool sp = v >= 1.0f; vst[p][2] = sp ? 0.f : v; q2 = __ballot(sp); }
      { float v = vst[p][3]; v = fmaf(0.5f, acc[3] - v, v); bool sp = v >= 1.0f; vst[p][3] = sp ? 0.f : v; q3 = __ballot(sp); }
      const u64 sel = (pr == 0) ? q0 : ((pr == 1) ? q1 : ((pr == 2) ? q2 : q3));
      word |= (uint)((sel >> (pg * 16)) & 0xFFFFull) << (p * 16);
    }
    if (lane < 16)
      m1[((size_t)t * 8 + w) * BATCH + b0 + lane] = word;

    // staging: write t+1 (held in f1) into the other buffer; issue load t+3
    if (ldr) {
      float4 wv4 = f1; f1 = f2;
      if (t + 3 < S_STEPS) f2 = *(const float4*)(src + (t + 3) * 40);
      if (t + 1 < S_STEPS) {
        uint2 u; u.x = pkbf(wv4.x, wv4.y); u.y = pkbf(wv4.z, wv4.w);
        *(uint2*)((char*)&A_sh[cur ^ 1][0] + wbyte) = u;
      }
    }
    __syncthreads();
  }
}

// ---------------------------------------------------------------------------
// k_scanrec: fused layers 2+3+readout. grid 256 x 256, block = 8 batches.
// W2,W3 bf16 in LDS (160 KB). Masks from m1 as wave-uniform u32 words,
// readfirstlane-pinned, processed by fully-static scalar while loops
// (NO runtime-indexed mask arrays -> no scratch). s2 exchanged via 256B LDS
// with an any-spike flag (layer 3 gather skipped when s2 silent).
// Counts stay in registers; in-block readout + log_softmax writes out.
// ---------------------------------------------------------------------------
__global__ __launch_bounds__(256) void k_scanrec(
    const float* __restrict__ W2, const float* __restrict__ b2,
    const float* __restrict__ W3, const float* __restrict__ b3,
    const float* __restrict__ Wr, const float* __restrict__ br,
    const uint* __restrict__ m1, float* __restrict__ out)
{
  extern __shared__ char smem[];
  ushort* W2s = (ushort*)smem;                 // 80,000 B
  ushort* W3s = (ushort*)(smem + 80000);       // 80,000 B
  u64*    ex  = (u64*)(smem + 160000);         // 8 batches x 4 words = 256 B
  float*  red = (float*)(smem + 160256);       // 96 f32 = 384 B
  int*    anyf = (int*)(smem + 160640);        // 2 ints (t-parity ping-pong)

  const int tid  = threadIdx.x;
  const int lane = tid & 63;
  const int wv   = tid >> 6;
  const int b0   = blockIdx.x * 8;
  const bool act = tid < HID;

  // stage W2, W3 as bf16 (float4 loads, 8B LDS writes)
  {
    const float4* g = (const float4*)W2;
#pragma unroll 4
    for (int i = tid; i < (HID * HID) / 4; i += 256) {
      float4 v = g[i];
      uint2 u; u.x = pkbf(v.x, v.y); u.y = pkbf(v.z, v.w);
      *(uint2*)&W2s[i * 4] = u;
    }
  }
  {
    const float4* g = (const float4*)W3;
#pragma unroll 4
    for (int i = tid; i < (HID * HID) / 4; i += 256) {
      float4 v = g[i];
      uint2 u; u.x = pkbf(v.x, v.y); u.y = pkbf(v.z, v.w);
      *(uint2*)&W3s[i * 4] = u;
    }
  }
  if (tid == 0) { anyf[0] = 0; anyf[1] = 0; }

  const float bias2 = act ? b2[tid] : 0.0f;
  const float bias3 = act ? b3[tid] : 0.0f;
  float v2[8] = {0,0,0,0,0,0,0,0};
  float v3[8] = {0,0,0,0,0,0,0,0};
  float cnt[8] = {0,0,0,0,0,0,0,0};

  // depth-1 mask prefetch (t=0): 8 words x 8 batches as uint4 pairs
  uint4 nxa[8], nxb[8];
#pragma unroll
  for (int ww = 0; ww < 8; ++ww) {
    const uint* mp = m1 + (size_t)ww * BATCH + b0;
    nxa[ww] = *(const uint4*)mp;
    nxb[ww] = *(const uint4*)(mp + 4);
  }
  __syncthreads();

#pragma unroll 1
  for (int t = 0; t < S_STEPS; ++t) {
    uint4 ca[8], cb[8];
#pragma unroll
    for (int ww = 0; ww < 8; ++ww) { ca[ww] = nxa[ww]; cb[ww] = nxb[ww]; }
    if (t + 1 < S_STEPS) {
#pragma unroll
      for (int ww = 0; ww < 8; ++ww) {
        const uint* mp = m1 + ((size_t)(t + 1) * 8 + ww) * BATCH + b0;
        nxa[ww] = *(const uint4*)mp;
        nxb[ww] = *(const uint4*)(mp + 4);
      }
    }

    // ---- layer 2: sparse masked row-sums, scalar whiles on SGPR words ----
    float a2[8];
#pragma unroll
    for (int i = 0; i < 8; ++i) a2[i] = bias2;
#define SP2(VAL, I)                                                            \
    { uint q = __builtin_amdgcn_readfirstlane(VAL);                            \
      while (q) { int k = ww * 32 + __builtin_ctz(q); q &= q - 1;              \
                  a2[I] += bf2f(W2s[k * HID + tid]); } }
#pragma unroll
    for (int ww = 0; ww < 8; ++ww) {
      SP2(ca[ww].x, 0) SP2(ca[ww].y, 1) SP2(ca[ww].z, 2) SP2(ca[ww].w, 3)
      SP2(cb[ww].x, 4) SP2(cb[ww].y, 5) SP2(cb[ww].z, 6) SP2(cb[ww].w, 7)
    }
#undef SP2

    // ---- LIF2 + ballot -> LDS exchange + any-spike flag ----
#pragma unroll
    for (int i = 0; i < 8; ++i) {
      float vv = v2[i];
      vv = fmaf(0.5f, a2[i] - vv, vv);
      bool sp = act && (vv >= 1.0f);
      v2[i] = sp ? 0.0f : vv;
      u64 q = __ballot(sp);
      if (lane == 0) { ex[i * 4 + wv] = q; if (q) anyf[t & 1] = 1; }
    }
    __syncthreads();
    const int any2 = anyf[t & 1];
    if (tid == 0) anyf[(t + 1) & 1] = 0;   // safe: next write is after barrier2

    // ---- layer 3: gather only if any s2 spike (essentially never) ----
    float a3[8];
#pragma unroll
    for (int i = 0; i < 8; ++i) a3[i] = bias3;
    if (any2) {
#pragma unroll
      for (int i = 0; i < 8; ++i) {
#pragma unroll
        for (int w4 = 0; w4 < 4; ++w4) {
          u64 m = ex[i * 4 + w4];
          uint qlo = __builtin_amdgcn_readfirstlane((uint)m);
          uint qhi = __builtin_amdgcn_readfirstlane((uint)(m >> 32));
          while (qlo) { int k = w4 * 64      + __builtin_ctz(qlo); qlo &= qlo - 1; a3[i] += bf2f(W3s[k * HID + tid]); }
          while (qhi) { int k = w4 * 64 + 32 + __builtin_ctz(qhi); qhi &= qhi - 1; a3[i] += bf2f(W3s[k * HID + tid]); }
        }
      }
    }
#pragma unroll
    for (int i = 0; i < 8; ++i) {
      float vv = v3[i];
      vv = fmaf(0.5f, a3[i] - vv, vv);
      bool sp = act && (vv >= 1.0f);
      v3[i] = sp ? 0.0f : vv;
      cnt[i] += sp ? 1.0f : 0.0f;
    }
    __syncthreads();
  }

  // ---- in-block readout: out[b] = log_softmax(cnt/101 @ Wr + br) ----
  if (tid < 96) red[tid] = 0.0f;
  __syncthreads();
  if (act) {
    float wr[DOUT];
#pragma unroll
    for (int j = 0; j < DOUT; ++j) wr[j] = Wr[tid * DOUT + j];
#pragma unroll
    for (int i = 0; i < 8; ++i) {
      float ci = cnt[i];
#pragma unroll
      for (int j = 0; j < DOUT; ++j) atomicAdd(&red[i * DOUT + j], ci * wr[j]);
    }
  }
  __syncthreads();
  if (tid < 8) {
    float o[DOUT];
#pragma unroll
    for (int j = 0; j < DOUT; ++j) o[j] = red[tid * DOUT + j] * (1.0f / 101.0f) + br[j];
    float mx = o[0];
#pragma unroll
    for (int j = 1; j < DOUT; ++j) mx = fmaxf(mx, o[j]);
    float s = 0.0f;
#pragma unroll
    for (int j = 0; j < DOUT; ++j) s += expf(o[j] - mx);
    float ls = logf(s);
    float* op = out + (size_t)(b0 + tid) * DOUT;
#pragma unroll
    for (int j = 0; j < DOUT; ++j) op[j] = o[j] - mx - ls;
  }
}

// ---------------------------------------------------------------------------
extern "C" void kernel_launch(void* const* d_in, const int* in_sizes, int n_in,
                              void* d_out, int out_size, void* d_ws, size_t ws_size,
                              hipStream_t stream)
{
  const float* x  = (const float*)d_in[0];
  const float* W1 = (const float*)d_in[1];
  const float* b1 = (const float*)d_in[2];
  const float* W2 = (const float*)d_in[3];
  const float* b2 = (const float*)d_in[4];
  const float* W3 = (const float*)d_in[5];
  const float* b3 = (const float*)d_in[6];
  const float* Wr = (const float*)d_in[7];
  const float* br = (const float*)d_in[8];
  float* out = (float*)d_out;

  // workspace: m1 [101][8][2048] u32 = 6,619,136 B
  uint* m1 = (uint*)d_ws;

  const int lds = 160648;
  hipFuncSetAttribute((const void*)k_scanrec,
                      hipFuncAttributeMaxDynamicSharedMemorySize, lds);

  k_l1<<<BATCH / 16, 512, 0, stream>>>(x, W1, b1, m1);
  k_scanrec<<<BATCH / 8, 256, lds, stream>>>(W2, b2, W3, b3, Wr, br, m1, out);
}